// Round 2
// 1568.777 us; speedup vs baseline: 1.5075x; 1.5075x over previous
//
#include <hip/hip_runtime.h>
#include <math.h>

#define N_POINTS 524288
#define NLV      16
#define TSZ      524288
#define TMASK    (TSZ - 1)
#define ASTART   5                  // levels >= ASTART: backward via in-register coeffs
#define NA       (NLV - ASTART)     // 11

static_assert(NA == 11, "NA mismatch");

struct Params { int res[NLV]; };

// Non-temporal store helper: outputs are write-once, keep them out of L2 so the
// hash-table gather lines survive longer.
__device__ __forceinline__ void stnt(float v, float* p) { __builtin_nontemporal_store(v, p); }

// ---- per-level forward gather: enc pair (bit-exact order) + optional backward coeffs.
// HASHED / STOREA are compile-time so every array index at the call site is constant
// (guaranteed SROA: the previous version's scratch-resident arrays were the bottleneck).
template<bool HASHED, bool STOREA>
__device__ __forceinline__ void lv_fwd(const float2* __restrict__ lt, const int res,
                                       const float xn0, const float xn1, const float xn2,
                                       float& e0o, float& e1o,
                                       float& o0x, float& o0y, float& o0z,
                                       float& o1x, float& o1y, float& o1z)
{
#pragma clang fp contract(off)
    const float rf = (float)(res - 1);
    const float px = xn0 * rf, py = xn1 * rf, pz = xn2 * rf;
    const float bx = floorf(px), by = floorf(py), bz = floorf(pz);
    const float fx = px - bx, fy = py - by, fz = pz - bz;
    const int r1 = res - 1;
    const int ix = (int)bx, iy = (int)by, iz = (int)bz;
    const int cx0 = min(max(ix, 0), r1),     cx1 = min(max(ix + 1, 0), r1);
    const int cy0 = min(max(iy, 0), r1),     cy1 = min(max(iy + 1, 0), r1);
    const int cz0 = min(max(iz, 0), r1),     cz1 = min(max(iz + 1, 0), r1);
    unsigned i000, i001, i010, i011, i100, i101, i110, i111;
    if constexpr (HASHED) {
        // hoisted: 3 muls per level instead of 16
        const unsigned hx0 = (unsigned)cx0, hx1 = (unsigned)cx1;
        const unsigned hy0 = (unsigned)cy0 * 2654435761u, hy1 = (unsigned)cy1 * 2654435761u;
        const unsigned hz0 = (unsigned)cz0 * 805459861u,  hz1 = (unsigned)cz1 * 805459861u;
        const unsigned e00 = hy0 ^ hz0, e01 = hy0 ^ hz1, e10 = hy1 ^ hz0, e11 = hy1 ^ hz1;
        i000 = (hx0 ^ e00) & TMASK; i001 = (hx0 ^ e01) & TMASK;
        i010 = (hx0 ^ e10) & TMASK; i011 = (hx0 ^ e11) & TMASK;
        i100 = (hx1 ^ e00) & TMASK; i101 = (hx1 ^ e01) & TMASK;
        i110 = (hx1 ^ e10) & TMASK; i111 = (hx1 ^ e11) & TMASK;
    } else {
        const int b00 = res * (cy0 + res * cz0), b01 = res * (cy0 + res * cz1);
        const int b10 = res * (cy1 + res * cz0), b11 = res * (cy1 + res * cz1);
        i000 = (unsigned)(cx0 + b00); i001 = (unsigned)(cx0 + b01);
        i010 = (unsigned)(cx0 + b10); i011 = (unsigned)(cx0 + b11);
        i100 = (unsigned)(cx1 + b00); i101 = (unsigned)(cx1 + b01);
        i110 = (unsigned)(cx1 + b10); i111 = (unsigned)(cx1 + b11);
    }
    const float2 t000 = lt[i000], t001 = lt[i001], t010 = lt[i010], t011 = lt[i011];
    const float2 t100 = lt[i100], t101 = lt[i101], t110 = lt[i110], t111 = lt[i111];
    const float gx0 = 1.0f - fx, gx1 = fx;
    const float gy0 = 1.0f - fy, gy1 = fy;
    const float gz0 = 1.0f - fz, gz1 = fz;
    // pxy(ox,oy) == wx*wy bitwise; w = (wx*wy)*wz — identical rounding to the ref.
    const float pxy00 = gx0 * gy0, pxy01 = gx0 * gy1, pxy10 = gx1 * gy0, pxy11 = gx1 * gy1;
    const float w000 = pxy00 * gz0, w001 = pxy00 * gz1, w010 = pxy01 * gz0, w011 = pxy01 * gz1;
    const float w100 = pxy10 * gz0, w101 = pxy10 * gz1, w110 = pxy11 * gz0, w111 = pxy11 * gz1;
    // corner order c = 0..7 (ox=c>>2, oy=c>>1&1, oz=c&1), separate mul/add (bit-exact)
    float e0 = 0.0f, e1 = 0.0f;
    e0 = e0 + w000 * t000.x; e1 = e1 + w000 * t000.y;
    e0 = e0 + w001 * t001.x; e1 = e1 + w001 * t001.y;
    e0 = e0 + w010 * t010.x; e1 = e1 + w010 * t010.y;
    e0 = e0 + w011 * t011.x; e1 = e1 + w011 * t011.y;
    e0 = e0 + w100 * t100.x; e1 = e1 + w100 * t100.y;
    e0 = e0 + w101 * t101.x; e1 = e1 + w101 * t101.y;
    e0 = e0 + w110 * t110.x; e1 = e1 + w110 * t110.y;
    e0 = e0 + w111 * t111.x; e1 = e1 + w111 * t111.y;
    e0o = e0; e1o = e1;
    if constexpr (STOREA) {
        // backward coeffs: a?x = sum_c (ox? +wyz : -wyz) * t;  etc. (value-continuous: fmaf ok)
        const float pyz00 = gy0 * gz0, pyz01 = gy0 * gz1, pyz10 = gy1 * gz0, pyz11 = gy1 * gz1;
        const float pxz00 = gx0 * gz0, pxz01 = gx0 * gz1, pxz10 = gx1 * gz0, pxz11 = gx1 * gz1;
        float a0x = 0.f, a0y = 0.f, a0z = 0.f, a1x = 0.f, a1y = 0.f, a1z = 0.f;
        // c=0 (0,0,0)
        a0x = fmaf(-pyz00, t000.x, a0x); a1x = fmaf(-pyz00, t000.y, a1x);
        a0y = fmaf(-pxz00, t000.x, a0y); a1y = fmaf(-pxz00, t000.y, a1y);
        a0z = fmaf(-pxy00, t000.x, a0z); a1z = fmaf(-pxy00, t000.y, a1z);
        // c=1 (0,0,1)
        a0x = fmaf(-pyz01, t001.x, a0x); a1x = fmaf(-pyz01, t001.y, a1x);
        a0y = fmaf(-pxz01, t001.x, a0y); a1y = fmaf(-pxz01, t001.y, a1y);
        a0z = fmaf( pxy00, t001.x, a0z); a1z = fmaf( pxy00, t001.y, a1z);
        // c=2 (0,1,0)
        a0x = fmaf(-pyz10, t010.x, a0x); a1x = fmaf(-pyz10, t010.y, a1x);
        a0y = fmaf( pxz00, t010.x, a0y); a1y = fmaf( pxz00, t010.y, a1y);
        a0z = fmaf(-pxy01, t010.x, a0z); a1z = fmaf(-pxy01, t010.y, a1z);
        // c=3 (0,1,1)
        a0x = fmaf(-pyz11, t011.x, a0x); a1x = fmaf(-pyz11, t011.y, a1x);
        a0y = fmaf( pxz01, t011.x, a0y); a1y = fmaf( pxz01, t011.y, a1y);
        a0z = fmaf( pxy01, t011.x, a0z); a1z = fmaf( pxy01, t011.y, a1z);
        // c=4 (1,0,0)
        a0x = fmaf( pyz00, t100.x, a0x); a1x = fmaf( pyz00, t100.y, a1x);
        a0y = fmaf(-pxz10, t100.x, a0y); a1y = fmaf(-pxz10, t100.y, a1y);
        a0z = fmaf(-pxy10, t100.x, a0z); a1z = fmaf(-pxy10, t100.y, a1z);
        // c=5 (1,0,1)
        a0x = fmaf( pyz01, t101.x, a0x); a1x = fmaf( pyz01, t101.y, a1x);
        a0y = fmaf(-pxz11, t101.x, a0y); a1y = fmaf(-pxz11, t101.y, a1y);
        a0z = fmaf( pxy10, t101.x, a0z); a1z = fmaf( pxy10, t101.y, a1z);
        // c=6 (1,1,0)
        a0x = fmaf( pyz10, t110.x, a0x); a1x = fmaf( pyz10, t110.y, a1x);
        a0y = fmaf( pxz10, t110.x, a0y); a1y = fmaf( pxz10, t110.y, a1y);
        a0z = fmaf(-pxy11, t110.x, a0z); a1z = fmaf(-pxy11, t110.y, a1z);
        // c=7 (1,1,1)
        a0x = fmaf( pyz11, t111.x, a0x); a1x = fmaf( pyz11, t111.y, a1x);
        a0y = fmaf( pxz11, t111.x, a0y); a1y = fmaf( pxz11, t111.y, a1y);
        a0z = fmaf( pxy11, t111.x, a0z); a1z = fmaf( pxy11, t111.y, a1z);
        o0x = a0x; o0y = a0y; o0z = a0z; o1x = a1x; o1y = a1y; o1z = a1z;
    }
}

// ---- backward re-gather for dense (L2-hot) low levels ----
__device__ __forceinline__ void lv_bwd_dense(const float2* __restrict__ lt, const int res,
                                             const float xn0, const float xn1, const float xn2,
                                             const float g0, const float g1,
                                             float& gx, float& gy, float& gz)
{
    const float rf = (float)(res - 1);
    const float px = xn0 * rf, py = xn1 * rf, pz = xn2 * rf;
    const float bx = floorf(px), by = floorf(py), bz = floorf(pz);
    const float fx = px - bx, fy = py - by, fz = pz - bz;
    const int r1 = res - 1;
    const int ix = (int)bx, iy = (int)by, iz = (int)bz;
    const int cx0 = min(max(ix, 0), r1),     cx1 = min(max(ix + 1, 0), r1);
    const int cy0 = min(max(iy, 0), r1),     cy1 = min(max(iy + 1, 0), r1);
    const int cz0 = min(max(iz, 0), r1),     cz1 = min(max(iz + 1, 0), r1);
    const int b00 = res * (cy0 + res * cz0), b01 = res * (cy0 + res * cz1);
    const int b10 = res * (cy1 + res * cz0), b11 = res * (cy1 + res * cz1);
    const float2 t000 = lt[cx0 + b00], t001 = lt[cx0 + b01], t010 = lt[cx0 + b10], t011 = lt[cx0 + b11];
    const float2 t100 = lt[cx1 + b00], t101 = lt[cx1 + b01], t110 = lt[cx1 + b10], t111 = lt[cx1 + b11];
    const float gx0 = 1.0f - fx, gx1 = fx;
    const float gy0 = 1.0f - fy, gy1 = fy;
    const float gz0 = 1.0f - fz, gz1 = fz;
    const float pyz00 = gy0 * gz0, pyz01 = gy0 * gz1, pyz10 = gy1 * gz0, pyz11 = gy1 * gz1;
    const float pxz00 = gx0 * gz0, pxz01 = gx0 * gz1, pxz10 = gx1 * gz0, pxz11 = gx1 * gz1;
    const float pxy00 = gx0 * gy0, pxy01 = gx0 * gy1, pxy10 = gx1 * gy0, pxy11 = gx1 * gy1;
    const float s000 = fmaf(g0, t000.x, g1 * t000.y);
    const float s001 = fmaf(g0, t001.x, g1 * t001.y);
    const float s010 = fmaf(g0, t010.x, g1 * t010.y);
    const float s011 = fmaf(g0, t011.x, g1 * t011.y);
    const float s100 = fmaf(g0, t100.x, g1 * t100.y);
    const float s101 = fmaf(g0, t101.x, g1 * t101.y);
    const float s110 = fmaf(g0, t110.x, g1 * t110.y);
    const float s111 = fmaf(g0, t111.x, g1 * t111.y);
    float lx = 0.f, ly = 0.f, lz = 0.f;
    lx = fmaf(-pyz00, s000, lx); ly = fmaf(-pxz00, s000, ly); lz = fmaf(-pxy00, s000, lz);
    lx = fmaf(-pyz01, s001, lx); ly = fmaf(-pxz01, s001, ly); lz = fmaf( pxy00, s001, lz);
    lx = fmaf(-pyz10, s010, lx); ly = fmaf( pxz00, s010, ly); lz = fmaf(-pxy01, s010, lz);
    lx = fmaf(-pyz11, s011, lx); ly = fmaf( pxz01, s011, ly); lz = fmaf( pxy01, s011, lz);
    lx = fmaf( pyz00, s100, lx); ly = fmaf(-pxz10, s100, ly); lz = fmaf(-pxy10, s100, lz);
    lx = fmaf( pyz01, s101, lx); ly = fmaf(-pxz11, s101, ly); lz = fmaf( pxy10, s101, lz);
    lx = fmaf( pyz10, s110, lx); ly = fmaf( pxz10, s110, ly); lz = fmaf(-pxy11, s110, lz);
    lx = fmaf( pyz11, s111, lx); ly = fmaf( pxz11, s111, ly); lz = fmaf( pxy11, s111, lz);
    gx = fmaf(lx, rf, gx); gy = fmaf(ly, rf, gy); gz = fmaf(lz, rf, gz);
}

// launch_bounds(256,3): VGPR cap ~168 — enough headroom that the ~120-float live set
// (enc 32 + A 66 + hd 16) never spills. Previous (256,4) version ended scratch-resident.
__global__ __launch_bounds__(256, 3)
void nerf_fused(const float* __restrict__ x,
                const float* __restrict__ tables,
                const float* __restrict__ ws0,
                const float* __restrict__ ws1,
                const float* __restrict__ wc0,
                const float* __restrict__ wc1,
                const float* __restrict__ wc2,
                const float* __restrict__ wn0,
                const float* __restrict__ wn1,
                const float* __restrict__ wm0,
                const float* __restrict__ bm0,
                const float* __restrict__ wm1,
                const float* __restrict__ bm1,
                float* __restrict__ out,
                Params P)
{
    const int n = blockIdx.x * 256 + threadIdx.x;
    if (n >= N_POINTS) return;

    const float x0 = x[(size_t)n * 6 + 0];
    const float x1 = x[(size_t)n * 6 + 1];
    const float x2 = x[(size_t)n * 6 + 2];
    const float xn0 = fminf(fmaxf((x0 + 1.0f) * 0.5f, 0.0f), 1.0f);
    const float xn1 = fminf(fmaxf((x1 + 1.0f) * 0.5f, 0.0f), 1.0f);
    const float xn2 = fminf(fmaxf((x2 + 1.0f) * 0.5f, 0.0f), 1.0f);

    const float2* __restrict__ tb = (const float2*)tables;

    float enc[32];
    float A0x[NA], A0y[NA], A0z[NA], A1x[NA], A1y[NA], A1z[NA];
    float dmy;

    // levels 0..5 dense (res^3 <= T for res<=80), levels 6..15 hashed (res>=111).
    // The dense/hashed boundary is robust to +-1 in res so it is safe at compile time.
#define FWD_NA(L) lv_fwd<false, false>(tb + (size_t)(L) * TSZ, P.res[L], xn0, xn1, xn2, \
                                       enc[2*(L)], enc[2*(L)+1], dmy, dmy, dmy, dmy, dmy, dmy)
#define FWD_A(L, H) lv_fwd<H, true>(tb + (size_t)(L) * TSZ, P.res[L], xn0, xn1, xn2,   \
                                    enc[2*(L)], enc[2*(L)+1],                           \
                                    A0x[(L)-ASTART], A0y[(L)-ASTART], A0z[(L)-ASTART],  \
                                    A1x[(L)-ASTART], A1y[(L)-ASTART], A1z[(L)-ASTART])
    FWD_NA(0); FWD_NA(1); FWD_NA(2); FWD_NA(3); FWD_NA(4);
    FWD_A(5, false);
    FWD_A(6, true);  FWD_A(7, true);  FWD_A(8, true);  FWD_A(9, true);  FWD_A(10, true);
    FWD_A(11, true); FWD_A(12, true); FWD_A(13, true); FWD_A(14, true); FWD_A(15, true);
#undef FWD_NA
#undef FWD_A

    // ---- density MLP: k rolled (uniform scalar weight loads), arrays static-indexed ----
    float hd[16];
    #pragma unroll
    for (int m = 0; m < 16; ++m) hd[m] = 0.0f;
    unsigned long long mask = 0ull;
    {
        #pragma clang fp contract(off)
        for (int k = 0; k < 64; ++k) {
            float a = 0.0f;
            #pragma unroll
            for (int j = 0; j < 32; ++j) {
                const float p = enc[j] * ws0[j * 64 + k];
                a = a + p;
            }
            const float hr = fmaxf(a, 0.0f);
            #pragma unroll
            for (int m = 0; m < 16; ++m) hd[m] = fmaf(hr, ws1[k * 16 + m], hd[m]);
            if (a > 0.0f) mask |= (1ull << k);
        }
    }
    const float sigma = hd[0];

    // ---- genc[32] = ws0 @ (mask .* ws1[:,0]) ----
    float genc[32];
    #pragma unroll
    for (int j = 0; j < 32; ++j) genc[j] = 0.0f;
    for (int k = 0; k < 64; ++k) {
        const float ghk = ((mask >> k) & 1ull) ? ws1[k * 16] : 0.0f;
        #pragma unroll
        for (int j = 0; j < 32; ++j) genc[j] = fmaf(ws0[j * 64 + k], ghk, genc[j]);
    }

    // ---- gradient: dense low levels re-gathered (L2-hot), high levels from A ----
    float gx = 0.0f, gy = 0.0f, gz = 0.0f;
    lv_bwd_dense(tb + 0 * (size_t)TSZ, P.res[0], xn0, xn1, xn2, genc[0], genc[1], gx, gy, gz);
    lv_bwd_dense(tb + 1 * (size_t)TSZ, P.res[1], xn0, xn1, xn2, genc[2], genc[3], gx, gy, gz);
    lv_bwd_dense(tb + 2 * (size_t)TSZ, P.res[2], xn0, xn1, xn2, genc[4], genc[5], gx, gy, gz);
    lv_bwd_dense(tb + 3 * (size_t)TSZ, P.res[3], xn0, xn1, xn2, genc[6], genc[7], gx, gy, gz);
    lv_bwd_dense(tb + 4 * (size_t)TSZ, P.res[4], xn0, xn1, xn2, genc[8], genc[9], gx, gy, gz);
    #pragma unroll
    for (int l = ASTART; l < NLV; ++l) {
        const int i = l - ASTART;
        const float rf = (float)(P.res[l] - 1);
        const float g0 = genc[2 * l], g1 = genc[2 * l + 1];
        gx = fmaf(rf, fmaf(g0, A0x[i], g1 * A1x[i]), gx);
        gy = fmaf(rf, fmaf(g0, A0y[i], g1 * A1y[i]), gy);
        gz = fmaf(rf, fmaf(g0, A0z[i], g1 * A1z[i]), gz);
    }
    gx *= 0.5f; gy *= 0.5f; gz *= 0.5f;

    const float gnorm = sqrtf(gx * gx + gy * gy + gz * gz);
    const float ginv = 1.0f / fmaxf(gnorm, 1e-8f);

    float geo[15];
    #pragma unroll
    for (int j = 0; j < 15; ++j) geo[j] = hd[1 + j];

    // ---- pred_normal = l2_normalize(relu(geo @ wn0) @ wn1) ----
    float pn0 = 0.0f, pn1 = 0.0f, pn2 = 0.0f;
    for (int k = 0; k < 64; ++k) {
        float a = 0.0f;
        #pragma unroll
        for (int j = 0; j < 15; ++j) a = fmaf(geo[j], wn0[j * 64 + k], a);
        a = fmaxf(a, 0.0f);
        pn0 = fmaf(a, wn1[k * 3 + 0], pn0);
        pn1 = fmaf(a, wn1[k * 3 + 1], pn1);
        pn2 = fmaf(a, wn1[k * 3 + 2], pn2);
    }
    const float pnorm = sqrtf(pn0 * pn0 + pn1 * pn1 + pn2 * pn2);
    const float pinv = 1.0f / fmaxf(pnorm, 1e-8f);

    // ---- spherical harmonics of d (loaded late to cut pressure in the gather phase) ----
    const float dx = x[(size_t)n * 6 + 3];
    const float dy = x[(size_t)n * 6 + 4];
    const float dz = x[(size_t)n * 6 + 5];
    float sh[16];
    const float xy = dx * dy, xz = dx * dz, yz = dy * dz;
    const float x2s = dx * dx, y2s = dy * dy, z2s = dz * dz;
    sh[0]  = 0.28209479177387814f;
    sh[1]  = -0.48860251190291987f * dy;
    sh[2]  =  0.48860251190291987f * dz;
    sh[3]  = -0.48860251190291987f * dx;
    sh[4]  =  1.0925484305920792f * xy;
    sh[5]  = -1.0925484305920792f * yz;
    sh[6]  =  0.94617469575756f * z2s - 0.31539156525252005f;
    sh[7]  = -1.0925484305920792f * xz;
    sh[8]  =  0.5462742152960396f * (x2s - y2s);
    sh[9]  =  0.5900435899266435f * dy * (-3.0f * x2s + y2s);
    sh[10] =  2.890611442640554f * xy * dz;
    sh[11] =  0.4570457994644657f * dy * (1.0f - 5.0f * z2s);
    sh[12] =  0.3731763325901154f * dz * (5.0f * z2s - 3.0f);
    sh[13] =  0.4570457994644657f * dx * (1.0f - 5.0f * z2s);
    sh[14] =  1.445305721320277f * dz * (x2s - y2s);
    sh[15] =  0.5900435899266435f * dx * (x2s - 3.0f * y2s);

    // ---- color MLP: [sh, geo] (31) -> 64 -> 64 -> 3, sigmoid.
    //      Loop-interchanged: c1 never materialized as an indexed array (scratch-proof);
    //      cacc[k2] accumulation order over kc = 0..63 matches the reference exactly. ----
    float cacc[64];
    #pragma unroll
    for (int k = 0; k < 64; ++k) cacc[k] = 0.0f;
    for (int kc = 0; kc < 64; ++kc) {
        float a = 0.0f;
        #pragma unroll
        for (int j = 0; j < 16; ++j) a = fmaf(sh[j], wc0[j * 64 + kc], a);
        #pragma unroll
        for (int j = 0; j < 15; ++j) a = fmaf(geo[j], wc0[(16 + j) * 64 + kc], a);
        const float c1v = fmaxf(a, 0.0f);
        const float* __restrict__ wrow = wc1 + kc * 64;   // row is contiguous: wide scalar loads
        #pragma unroll
        for (int k2 = 0; k2 < 64; ++k2) cacc[k2] = fmaf(c1v, wrow[k2], cacc[k2]);
    }
    float r0 = 0.0f, r1 = 0.0f, r2 = 0.0f;
    #pragma unroll
    for (int k = 0; k < 64; ++k) {
        const float a = fmaxf(cacc[k], 0.0f);
        r0 = fmaf(a, wc2[k * 3 + 0], r0);
        r1 = fmaf(a, wc2[k * 3 + 1], r1);
        r2 = fmaf(a, wc2[k * 3 + 2], r2);
    }
    const float rgb0 = 1.0f / (1.0f + expf(-r0));
    const float rgb1 = 1.0f / (1.0f + expf(-r1));
    const float rgb2 = 1.0f / (1.0f + expf(-r2));

    // ---- mirror head ----
    float macc = 0.0f;
    for (int k = 0; k < 32; ++k) {
        float a = bm0[k];
        #pragma unroll
        for (int j = 0; j < 15; ++j) a = fmaf(geo[j], wm0[j * 32 + k], a);
        a = (a >= 0.0f) ? a : 0.01f * a;
        macc = fmaf(a, wm1[k], macc);
    }
    macc += bm1[0];
    const float mir = 1.0f / (1.0f + expf(-macc));

    // ---- write outputs (non-temporal: write-once stream, keep L2 for tables) ----
    const size_t N = (size_t)N_POINTS;
    stnt(sigma, &out[n]);
    #pragma unroll
    for (int j = 0; j < 15; ++j)
        stnt(geo[j], &out[N + (size_t)n * 15 + j]);
    stnt(-gx * ginv, &out[16 * N + (size_t)n * 3 + 0]);
    stnt(-gy * ginv, &out[16 * N + (size_t)n * 3 + 1]);
    stnt(-gz * ginv, &out[16 * N + (size_t)n * 3 + 2]);
    stnt(pn0 * pinv, &out[19 * N + (size_t)n * 3 + 0]);
    stnt(pn1 * pinv, &out[19 * N + (size_t)n * 3 + 1]);
    stnt(pn2 * pinv, &out[19 * N + (size_t)n * 3 + 2]);
    stnt(rgb0, &out[22 * N + (size_t)n * 3 + 0]);
    stnt(rgb1, &out[22 * N + (size_t)n * 3 + 1]);
    stnt(rgb2, &out[22 * N + (size_t)n * 3 + 2]);
    stnt(mir, &out[25 * N + n]);
}

extern "C" void kernel_launch(void* const* d_in, const int* in_sizes, int n_in,
                              void* d_out, int out_size, void* d_ws, size_t ws_size,
                              hipStream_t stream)
{
    // Replicate Python's RES computation bit-for-bit (same libm as the previous
    // passing kernel): PLS = exp2(log2(2048*BOUND/N_LEVELS)/(N_LEVELS-1)).
    Params P;
    const double PLS = exp2(log2(2048.0 * 1.0 / 16.0) / 15.0);
    for (int l = 0; l < NLV; ++l)
        P.res[l] = (int)floor(16.0 * pow(PLS, (double)l));

    nerf_fused<<<N_POINTS / 256, 256, 0, stream>>>(
        (const float*)d_in[0],   // x
        (const float*)d_in[1],   // tables
        (const float*)d_in[2],   // ws0
        (const float*)d_in[3],   // ws1
        (const float*)d_in[4],   // wc0
        (const float*)d_in[5],   // wc1
        (const float*)d_in[6],   // wc2
        (const float*)d_in[7],   // wn0
        (const float*)d_in[8],   // wn1
        (const float*)d_in[9],   // wm0
        (const float*)d_in[10],  // bm0
        (const float*)d_in[11],  // wm1
        (const float*)d_in[12],  // bm1
        (float*)d_out, P);
}

// Round 3
// 1469.680 us; speedup vs baseline: 1.6092x; 1.0674x over previous
//
#include <hip/hip_runtime.h>
#include <math.h>

#define N_POINTS 524288
#define NLV      16
#define TSZ      524288
#define TMASK    (TSZ - 1)
#define ASTART   5                  // levels >= ASTART: backward via in-register coeffs
#define NA       (NLV - ASTART)     // 11

static_assert(NA == 11, "NA mismatch");

struct Params { int res[NLV]; };

// Non-temporal store helper (held constant this round; write-amplification theory
// to be tested separately).
__device__ __forceinline__ void stnt(float v, float* p) { __builtin_nontemporal_store(v, p); }

// ============================================================================
// Software-pipelined gather: ISSUE (index math + fire 8 loads) is split from
// CONSUME (weights + accumulate). The kernel issues TWO levels' loads before
// consuming either -> 16 scattered loads in flight per wave instead of 8.
// R2 counters showed ~1.8 concurrent misses/wave (latency-starved).
// ============================================================================

template<bool HASHED>
__device__ __forceinline__ void lv_issue(const float2* __restrict__ lt, const int res,
                                         const float xn0, const float xn1, const float xn2,
                                         float2 (&t)[8],
                                         float& fxo, float& fyo, float& fzo)
{
#pragma clang fp contract(off)
    const float rf = (float)(res - 1);
    const float px = xn0 * rf, py = xn1 * rf, pz = xn2 * rf;
    const float bx = floorf(px), by = floorf(py), bz = floorf(pz);
    fxo = px - bx; fyo = py - by; fzo = pz - bz;
    const int r1 = res - 1;
    const int ix = (int)bx, iy = (int)by, iz = (int)bz;
    const int cx0 = min(max(ix, 0), r1),     cx1 = min(max(ix + 1, 0), r1);
    const int cy0 = min(max(iy, 0), r1),     cy1 = min(max(iy + 1, 0), r1);
    const int cz0 = min(max(iz, 0), r1),     cz1 = min(max(iz + 1, 0), r1);
    unsigned i000, i001, i010, i011, i100, i101, i110, i111;
    if constexpr (HASHED) {
        const unsigned hx0 = (unsigned)cx0, hx1 = (unsigned)cx1;
        const unsigned hy0 = (unsigned)cy0 * 2654435761u, hy1 = (unsigned)cy1 * 2654435761u;
        const unsigned hz0 = (unsigned)cz0 * 805459861u,  hz1 = (unsigned)cz1 * 805459861u;
        const unsigned e00 = hy0 ^ hz0, e01 = hy0 ^ hz1, e10 = hy1 ^ hz0, e11 = hy1 ^ hz1;
        i000 = (hx0 ^ e00) & TMASK; i001 = (hx0 ^ e01) & TMASK;
        i010 = (hx0 ^ e10) & TMASK; i011 = (hx0 ^ e11) & TMASK;
        i100 = (hx1 ^ e00) & TMASK; i101 = (hx1 ^ e01) & TMASK;
        i110 = (hx1 ^ e10) & TMASK; i111 = (hx1 ^ e11) & TMASK;
    } else {
        const int b00 = res * (cy0 + res * cz0), b01 = res * (cy0 + res * cz1);
        const int b10 = res * (cy1 + res * cz0), b11 = res * (cy1 + res * cz1);
        i000 = (unsigned)(cx0 + b00); i001 = (unsigned)(cx0 + b01);
        i010 = (unsigned)(cx0 + b10); i011 = (unsigned)(cx0 + b11);
        i100 = (unsigned)(cx1 + b00); i101 = (unsigned)(cx1 + b01);
        i110 = (unsigned)(cx1 + b10); i111 = (unsigned)(cx1 + b11);
    }
    // corner order c=0..7 (ox=c>>2, oy=(c>>1)&1, oz=c&1) — t[c] matches ref order
    t[0] = lt[i000]; t[1] = lt[i001]; t[2] = lt[i010]; t[3] = lt[i011];
    t[4] = lt[i100]; t[5] = lt[i101]; t[6] = lt[i110]; t[7] = lt[i111];
}

// Consume: bit-exact e-accumulation (separate mul/add, corner order c=0..7),
// optional backward coeffs (value-continuous: fmaf ok). Verbatim math from R2.
template<bool STOREA>
__device__ __forceinline__ void lv_consume(const float2 (&t)[8],
                                           const float fx, const float fy, const float fz,
                                           float& e0o, float& e1o,
                                           float& o0x, float& o0y, float& o0z,
                                           float& o1x, float& o1y, float& o1z)
{
#pragma clang fp contract(off)
    const float gx0 = 1.0f - fx, gx1 = fx;
    const float gy0 = 1.0f - fy, gy1 = fy;
    const float gz0 = 1.0f - fz, gz1 = fz;
    const float pxy00 = gx0 * gy0, pxy01 = gx0 * gy1, pxy10 = gx1 * gy0, pxy11 = gx1 * gy1;
    const float w000 = pxy00 * gz0, w001 = pxy00 * gz1, w010 = pxy01 * gz0, w011 = pxy01 * gz1;
    const float w100 = pxy10 * gz0, w101 = pxy10 * gz1, w110 = pxy11 * gz0, w111 = pxy11 * gz1;
    float e0 = 0.0f, e1 = 0.0f;
    e0 = e0 + w000 * t[0].x; e1 = e1 + w000 * t[0].y;
    e0 = e0 + w001 * t[1].x; e1 = e1 + w001 * t[1].y;
    e0 = e0 + w010 * t[2].x; e1 = e1 + w010 * t[2].y;
    e0 = e0 + w011 * t[3].x; e1 = e1 + w011 * t[3].y;
    e0 = e0 + w100 * t[4].x; e1 = e1 + w100 * t[4].y;
    e0 = e0 + w101 * t[5].x; e1 = e1 + w101 * t[5].y;
    e0 = e0 + w110 * t[6].x; e1 = e1 + w110 * t[6].y;
    e0 = e0 + w111 * t[7].x; e1 = e1 + w111 * t[7].y;
    e0o = e0; e1o = e1;
    if constexpr (STOREA) {
        const float pyz00 = gy0 * gz0, pyz01 = gy0 * gz1, pyz10 = gy1 * gz0, pyz11 = gy1 * gz1;
        const float pxz00 = gx0 * gz0, pxz01 = gx0 * gz1, pxz10 = gx1 * gz0, pxz11 = gx1 * gz1;
        float a0x = 0.f, a0y = 0.f, a0z = 0.f, a1x = 0.f, a1y = 0.f, a1z = 0.f;
        a0x = fmaf(-pyz00, t[0].x, a0x); a1x = fmaf(-pyz00, t[0].y, a1x);
        a0y = fmaf(-pxz00, t[0].x, a0y); a1y = fmaf(-pxz00, t[0].y, a1y);
        a0z = fmaf(-pxy00, t[0].x, a0z); a1z = fmaf(-pxy00, t[0].y, a1z);
        a0x = fmaf(-pyz01, t[1].x, a0x); a1x = fmaf(-pyz01, t[1].y, a1x);
        a0y = fmaf(-pxz01, t[1].x, a0y); a1y = fmaf(-pxz01, t[1].y, a1y);
        a0z = fmaf( pxy00, t[1].x, a0z); a1z = fmaf( pxy00, t[1].y, a1z);
        a0x = fmaf(-pyz10, t[2].x, a0x); a1x = fmaf(-pyz10, t[2].y, a1x);
        a0y = fmaf( pxz00, t[2].x, a0y); a1y = fmaf( pxz00, t[2].y, a1y);
        a0z = fmaf(-pxy01, t[2].x, a0z); a1z = fmaf(-pxy01, t[2].y, a1z);
        a0x = fmaf(-pyz11, t[3].x, a0x); a1x = fmaf(-pyz11, t[3].y, a1x);
        a0y = fmaf( pxz01, t[3].x, a0y); a1y = fmaf( pxz01, t[3].y, a1y);
        a0z = fmaf( pxy01, t[3].x, a0z); a1z = fmaf( pxy01, t[3].y, a1z);
        a0x = fmaf( pyz00, t[4].x, a0x); a1x = fmaf( pyz00, t[4].y, a1x);
        a0y = fmaf(-pxz10, t[4].x, a0y); a1y = fmaf(-pxz10, t[4].y, a1y);
        a0z = fmaf(-pxy10, t[4].x, a0z); a1z = fmaf(-pxy10, t[4].y, a1z);
        a0x = fmaf( pyz01, t[5].x, a0x); a1x = fmaf( pyz01, t[5].y, a1x);
        a0y = fmaf(-pxz11, t[5].x, a0y); a1y = fmaf(-pxz11, t[5].y, a1y);
        a0z = fmaf( pxy10, t[5].x, a0z); a1z = fmaf( pxy10, t[5].y, a1z);
        a0x = fmaf( pyz10, t[6].x, a0x); a1x = fmaf( pyz10, t[6].y, a1x);
        a0y = fmaf( pxz10, t[6].x, a0y); a1y = fmaf( pxz10, t[6].y, a1y);
        a0z = fmaf(-pxy11, t[6].x, a0z); a1z = fmaf(-pxy11, t[6].y, a1z);
        a0x = fmaf( pyz11, t[7].x, a0x); a1x = fmaf( pyz11, t[7].y, a1x);
        a0y = fmaf( pxz11, t[7].x, a0y); a1y = fmaf( pxz11, t[7].y, a1y);
        a0z = fmaf( pxy11, t[7].x, a0z); a1z = fmaf( pxy11, t[7].y, a1z);
        o0x = a0x; o0y = a0y; o0z = a0z; o1x = a1x; o1y = a1y; o1z = a1z;
    }
}

// backward consume for re-gathered dense levels (fmaf ok, verbatim math from R2)
__device__ __forceinline__ void bwd_consume(const float2 (&t)[8],
                                            const float fx, const float fy, const float fz,
                                            const float rf, const float g0, const float g1,
                                            float& gx, float& gy, float& gz)
{
    const float gx0 = 1.0f - fx, gx1 = fx;
    const float gy0 = 1.0f - fy, gy1 = fy;
    const float gz0 = 1.0f - fz, gz1 = fz;
    const float pyz00 = gy0 * gz0, pyz01 = gy0 * gz1, pyz10 = gy1 * gz0, pyz11 = gy1 * gz1;
    const float pxz00 = gx0 * gz0, pxz01 = gx0 * gz1, pxz10 = gx1 * gz0, pxz11 = gx1 * gz1;
    const float pxy00 = gx0 * gy0, pxy01 = gx0 * gy1, pxy10 = gx1 * gy0, pxy11 = gx1 * gy1;
    const float s000 = fmaf(g0, t[0].x, g1 * t[0].y);
    const float s001 = fmaf(g0, t[1].x, g1 * t[1].y);
    const float s010 = fmaf(g0, t[2].x, g1 * t[2].y);
    const float s011 = fmaf(g0, t[3].x, g1 * t[3].y);
    const float s100 = fmaf(g0, t[4].x, g1 * t[4].y);
    const float s101 = fmaf(g0, t[5].x, g1 * t[5].y);
    const float s110 = fmaf(g0, t[6].x, g1 * t[6].y);
    const float s111 = fmaf(g0, t[7].x, g1 * t[7].y);
    float lx = 0.f, ly = 0.f, lz = 0.f;
    lx = fmaf(-pyz00, s000, lx); ly = fmaf(-pxz00, s000, ly); lz = fmaf(-pxy00, s000, lz);
    lx = fmaf(-pyz01, s001, lx); ly = fmaf(-pxz01, s001, ly); lz = fmaf( pxy00, s001, lz);
    lx = fmaf(-pyz10, s010, lx); ly = fmaf( pxz00, s010, ly); lz = fmaf(-pxy01, s010, lz);
    lx = fmaf(-pyz11, s011, lx); ly = fmaf( pxz01, s011, ly); lz = fmaf( pxy01, s011, lz);
    lx = fmaf( pyz00, s100, lx); ly = fmaf(-pxz10, s100, ly); lz = fmaf(-pxy10, s100, lz);
    lx = fmaf( pyz01, s101, lx); ly = fmaf(-pxz11, s101, ly); lz = fmaf( pxy10, s101, lz);
    lx = fmaf( pyz10, s110, lx); ly = fmaf( pxz10, s110, ly); lz = fmaf(-pxy11, s110, lz);
    lx = fmaf( pyz11, s111, lx); ly = fmaf( pxz11, s111, ly); lz = fmaf( pxy11, s111, lz);
    gx = fmaf(lx, rf, gx); gy = fmaf(ly, rf, gy); gz = fmaf(lz, rf, gz);
}

// launch_bounds(256,4): R0/R2 evidence shows achieved occupancy tracks this arg
// (4 -> 44%, 3 -> 33%); VGPR target <=128 (pipelined peak ~120) keeps 16 waves/CU legal.
__global__ __launch_bounds__(256, 4)
void nerf_fused(const float* __restrict__ x,
                const float* __restrict__ tables,
                const float* __restrict__ ws0,
                const float* __restrict__ ws1,
                const float* __restrict__ wc0,
                const float* __restrict__ wc1,
                const float* __restrict__ wc2,
                const float* __restrict__ wn0,
                const float* __restrict__ wn1,
                const float* __restrict__ wm0,
                const float* __restrict__ bm0,
                const float* __restrict__ wm1,
                const float* __restrict__ bm1,
                float* __restrict__ out,
                Params P)
{
    const int n = blockIdx.x * 256 + threadIdx.x;
    if (n >= N_POINTS) return;

    const float x0 = x[(size_t)n * 6 + 0];
    const float x1 = x[(size_t)n * 6 + 1];
    const float x2 = x[(size_t)n * 6 + 2];
    const float xn0 = fminf(fmaxf((x0 + 1.0f) * 0.5f, 0.0f), 1.0f);
    const float xn1 = fminf(fmaxf((x1 + 1.0f) * 0.5f, 0.0f), 1.0f);
    const float xn2 = fminf(fmaxf((x2 + 1.0f) * 0.5f, 0.0f), 1.0f);

    const float2* __restrict__ tb = (const float2*)tables;

    float enc[32];
    float A0x[NA], A0y[NA], A0z[NA], A1x[NA], A1y[NA], A1z[NA];
    float dmy;

    // ---- forward: levels in pairs; issue both levels' 16 loads, then consume.
    {
        float2 tA[8], tB[8];
        float fxA, fyA, fzA, fxB, fyB, fzB;

#define PAIR(LA, HA, SA, LB, HB, SB)                                                     \
        lv_issue<HA>(tb + (size_t)(LA) * TSZ, P.res[LA], xn0, xn1, xn2, tA, fxA, fyA, fzA); \
        lv_issue<HB>(tb + (size_t)(LB) * TSZ, P.res[LB], xn0, xn1, xn2, tB, fxB, fyB, fzB); \
        if constexpr (SA)                                                                 \
            lv_consume<true>(tA, fxA, fyA, fzA, enc[2*(LA)], enc[2*(LA)+1],               \
                A0x[(LA)-ASTART], A0y[(LA)-ASTART], A0z[(LA)-ASTART],                     \
                A1x[(LA)-ASTART], A1y[(LA)-ASTART], A1z[(LA)-ASTART]);                    \
        else                                                                              \
            lv_consume<false>(tA, fxA, fyA, fzA, enc[2*(LA)], enc[2*(LA)+1],              \
                dmy, dmy, dmy, dmy, dmy, dmy);                                            \
        if constexpr (SB)                                                                 \
            lv_consume<true>(tB, fxB, fyB, fzB, enc[2*(LB)], enc[2*(LB)+1],               \
                A0x[(LB)-ASTART], A0y[(LB)-ASTART], A0z[(LB)-ASTART],                     \
                A1x[(LB)-ASTART], A1y[(LB)-ASTART], A1z[(LB)-ASTART]);                    \
        else                                                                              \
            lv_consume<false>(tB, fxB, fyB, fzB, enc[2*(LB)], enc[2*(LB)+1],              \
                dmy, dmy, dmy, dmy, dmy, dmy);

        PAIR(0,  false, false, 1,  false, false)
        PAIR(2,  false, false, 3,  false, false)
        PAIR(4,  false, false, 5,  false, true )
        PAIR(6,  true,  true,  7,  true,  true )
        PAIR(8,  true,  true,  9,  true,  true )
        PAIR(10, true,  true,  11, true,  true )
        PAIR(12, true,  true,  13, true,  true )
        PAIR(14, true,  true,  15, true,  true )
#undef PAIR
    }

    // ---- density MLP: k rolled (uniform scalar weight loads), arrays static-indexed ----
    float hd[16];
    #pragma unroll
    for (int m = 0; m < 16; ++m) hd[m] = 0.0f;
    unsigned long long mask = 0ull;
    {
        #pragma clang fp contract(off)
        for (int k = 0; k < 64; ++k) {
            float a = 0.0f;
            #pragma unroll
            for (int j = 0; j < 32; ++j) {
                const float p = enc[j] * ws0[j * 64 + k];
                a = a + p;
            }
            const float hr = fmaxf(a, 0.0f);
            #pragma unroll
            for (int m = 0; m < 16; ++m) hd[m] = fmaf(hr, ws1[k * 16 + m], hd[m]);
            if (a > 0.0f) mask |= (1ull << k);
        }
    }
    const float sigma = hd[0];

    // ---- backward dense levels: issue group {0,1,2} BEFORE the genc loop so the
    //      ~2k cycles of genc VALU hide those 24 scattered loads entirely. ----
    float gx = 0.0f, gy = 0.0f, gz = 0.0f;
    {
        float2 tA[8], tB[8], tC[8];
        float fxA, fyA, fzA, fxB, fyB, fzB, fxC, fyC, fzC;
        lv_issue<false>(tb + 0 * (size_t)TSZ, P.res[0], xn0, xn1, xn2, tA, fxA, fyA, fzA);
        lv_issue<false>(tb + 1 * (size_t)TSZ, P.res[1], xn0, xn1, xn2, tB, fxB, fyB, fzB);
        lv_issue<false>(tb + 2 * (size_t)TSZ, P.res[2], xn0, xn1, xn2, tC, fxC, fyC, fzC);

        // genc[32] = ws0 @ (mask .* ws1[:,0])
        float genc[32];
        #pragma unroll
        for (int j = 0; j < 32; ++j) genc[j] = 0.0f;
        for (int k = 0; k < 64; ++k) {
            const float ghk = ((mask >> k) & 1ull) ? ws1[k * 16] : 0.0f;
            #pragma unroll
            for (int j = 0; j < 32; ++j) genc[j] = fmaf(ws0[j * 64 + k], ghk, genc[j]);
        }

        bwd_consume(tA, fxA, fyA, fzA, (float)(P.res[0] - 1), genc[0], genc[1], gx, gy, gz);
        bwd_consume(tB, fxB, fyB, fzB, (float)(P.res[1] - 1), genc[2], genc[3], gx, gy, gz);
        bwd_consume(tC, fxC, fyC, fzC, (float)(P.res[2] - 1), genc[4], genc[5], gx, gy, gz);

        lv_issue<false>(tb + 3 * (size_t)TSZ, P.res[3], xn0, xn1, xn2, tA, fxA, fyA, fzA);
        lv_issue<false>(tb + 4 * (size_t)TSZ, P.res[4], xn0, xn1, xn2, tB, fxB, fyB, fzB);
        bwd_consume(tA, fxA, fyA, fzA, (float)(P.res[3] - 1), genc[6], genc[7], gx, gy, gz);
        bwd_consume(tB, fxB, fyB, fzB, (float)(P.res[4] - 1), genc[8], genc[9], gx, gy, gz);

        // high levels from in-register A coeffs
        #pragma unroll
        for (int l = ASTART; l < NLV; ++l) {
            const int i = l - ASTART;
            const float rf = (float)(P.res[l] - 1);
            const float g0 = genc[2 * l], g1 = genc[2 * l + 1];
            gx = fmaf(rf, fmaf(g0, A0x[i], g1 * A1x[i]), gx);
            gy = fmaf(rf, fmaf(g0, A0y[i], g1 * A1y[i]), gy);
            gz = fmaf(rf, fmaf(g0, A0z[i], g1 * A1z[i]), gz);
        }
    }
    gx *= 0.5f; gy *= 0.5f; gz *= 0.5f;

    const float gnorm = sqrtf(gx * gx + gy * gy + gz * gz);
    const float ginv = 1.0f / fmaxf(gnorm, 1e-8f);

    float geo[15];
    #pragma unroll
    for (int j = 0; j < 15; ++j) geo[j] = hd[1 + j];

    // ---- pred_normal = l2_normalize(relu(geo @ wn0) @ wn1) ----
    float pn0 = 0.0f, pn1 = 0.0f, pn2 = 0.0f;
    for (int k = 0; k < 64; ++k) {
        float a = 0.0f;
        #pragma unroll
        for (int j = 0; j < 15; ++j) a = fmaf(geo[j], wn0[j * 64 + k], a);
        a = fmaxf(a, 0.0f);
        pn0 = fmaf(a, wn1[k * 3 + 0], pn0);
        pn1 = fmaf(a, wn1[k * 3 + 1], pn1);
        pn2 = fmaf(a, wn1[k * 3 + 2], pn2);
    }
    const float pnorm = sqrtf(pn0 * pn0 + pn1 * pn1 + pn2 * pn2);
    const float pinv = 1.0f / fmaxf(pnorm, 1e-8f);

    // ---- spherical harmonics of d ----
    const float dx = x[(size_t)n * 6 + 3];
    const float dy = x[(size_t)n * 6 + 4];
    const float dz = x[(size_t)n * 6 + 5];
    float sh[16];
    const float xy = dx * dy, xz = dx * dz, yz = dy * dz;
    const float x2s = dx * dx, y2s = dy * dy, z2s = dz * dz;
    sh[0]  = 0.28209479177387814f;
    sh[1]  = -0.48860251190291987f * dy;
    sh[2]  =  0.48860251190291987f * dz;
    sh[3]  = -0.48860251190291987f * dx;
    sh[4]  =  1.0925484305920792f * xy;
    sh[5]  = -1.0925484305920792f * yz;
    sh[6]  =  0.94617469575756f * z2s - 0.31539156525252005f;
    sh[7]  = -1.0925484305920792f * xz;
    sh[8]  =  0.5462742152960396f * (x2s - y2s);
    sh[9]  =  0.5900435899266435f * dy * (-3.0f * x2s + y2s);
    sh[10] =  2.890611442640554f * xy * dz;
    sh[11] =  0.4570457994644657f * dy * (1.0f - 5.0f * z2s);
    sh[12] =  0.3731763325901154f * dz * (5.0f * z2s - 3.0f);
    sh[13] =  0.4570457994644657f * dx * (1.0f - 5.0f * z2s);
    sh[14] =  1.445305721320277f * dz * (x2s - y2s);
    sh[15] =  0.5900435899266435f * dx * (x2s - 3.0f * y2s);

    // ---- color MLP: [sh, geo] (31) -> 64 -> 64 -> 3, sigmoid. c1 never indexed
    //      as an array (loop-interchanged, bit-exact accumulation order). ----
    float cacc[64];
    #pragma unroll
    for (int k = 0; k < 64; ++k) cacc[k] = 0.0f;
    for (int kc = 0; kc < 64; ++kc) {
        float a = 0.0f;
        #pragma unroll
        for (int j = 0; j < 16; ++j) a = fmaf(sh[j], wc0[j * 64 + kc], a);
        #pragma unroll
        for (int j = 0; j < 15; ++j) a = fmaf(geo[j], wc0[(16 + j) * 64 + kc], a);
        const float c1v = fmaxf(a, 0.0f);
        const float* __restrict__ wrow = wc1 + kc * 64;
        #pragma unroll
        for (int k2 = 0; k2 < 64; ++k2) cacc[k2] = fmaf(c1v, wrow[k2], cacc[k2]);
    }
    float r0 = 0.0f, r1 = 0.0f, r2 = 0.0f;
    #pragma unroll
    for (int k = 0; k < 64; ++k) {
        const float a = fmaxf(cacc[k], 0.0f);
        r0 = fmaf(a, wc2[k * 3 + 0], r0);
        r1 = fmaf(a, wc2[k * 3 + 1], r1);
        r2 = fmaf(a, wc2[k * 3 + 2], r2);
    }
    const float rgb0 = 1.0f / (1.0f + expf(-r0));
    const float rgb1 = 1.0f / (1.0f + expf(-r1));
    const float rgb2 = 1.0f / (1.0f + expf(-r2));

    // ---- mirror head ----
    float macc = 0.0f;
    for (int k = 0; k < 32; ++k) {
        float a = bm0[k];
        #pragma unroll
        for (int j = 0; j < 15; ++j) a = fmaf(geo[j], wm0[j * 32 + k], a);
        a = (a >= 0.0f) ? a : 0.01f * a;
        macc = fmaf(a, wm1[k], macc);
    }
    macc += bm1[0];
    const float mir = 1.0f / (1.0f + expf(-macc));

    // ---- write outputs ----
    const size_t N = (size_t)N_POINTS;
    stnt(sigma, &out[n]);
    #pragma unroll
    for (int j = 0; j < 15; ++j)
        stnt(geo[j], &out[N + (size_t)n * 15 + j]);
    stnt(-gx * ginv, &out[16 * N + (size_t)n * 3 + 0]);
    stnt(-gy * ginv, &out[16 * N + (size_t)n * 3 + 1]);
    stnt(-gz * ginv, &out[16 * N + (size_t)n * 3 + 2]);
    stnt(pn0 * pinv, &out[19 * N + (size_t)n * 3 + 0]);
    stnt(pn1 * pinv, &out[19 * N + (size_t)n * 3 + 1]);
    stnt(pn2 * pinv, &out[19 * N + (size_t)n * 3 + 2]);
    stnt(rgb0, &out[22 * N + (size_t)n * 3 + 0]);
    stnt(rgb1, &out[22 * N + (size_t)n * 3 + 1]);
    stnt(rgb2, &out[22 * N + (size_t)n * 3 + 2]);
    stnt(mir, &out[25 * N + n]);
}

extern "C" void kernel_launch(void* const* d_in, const int* in_sizes, int n_in,
                              void* d_out, int out_size, void* d_ws, size_t ws_size,
                              hipStream_t stream)
{
    // Replicate Python's RES computation bit-for-bit:
    // PLS = exp2(log2(2048.0*BOUND/N_LEVELS)/(N_LEVELS-1)); RES[l] = floor(16*PLS**l)
    Params P;
    const double PLS = exp2(log2(2048.0 * 1.0 / 16.0) / 15.0);
    for (int l = 0; l < NLV; ++l)
        P.res[l] = (int)floor(16.0 * pow(PLS, (double)l));

    nerf_fused<<<N_POINTS / 256, 256, 0, stream>>>(
        (const float*)d_in[0],   // x
        (const float*)d_in[1],   // tables
        (const float*)d_in[2],   // ws0
        (const float*)d_in[3],   // ws1
        (const float*)d_in[4],   // wc0
        (const float*)d_in[5],   // wc1
        (const float*)d_in[6],   // wc2
        (const float*)d_in[7],   // wn0
        (const float*)d_in[8],   // wn1
        (const float*)d_in[9],   // wm0
        (const float*)d_in[10],  // bm0
        (const float*)d_in[11],  // wm1
        (const float*)d_in[12],  // bm1
        (float*)d_out, P);
}